// Round 17
// baseline (7373.631 us; speedup 1.0000x reference)
//
#include <hip/hip_runtime.h>
#include <math.h>

#define N_VEC   8192
#define EDIM    768
#define NCODES  1024
#define SKITERS 100
#define ROWS_PB 32
#define CHUNKS  (N_VEC / ROWS_PB)   // 256
#define DYN_LDS ((32 * NCODES + 128) * 4)

// ---------- agent-scope relaxed atomics (coherent at L3, no L2 wb/inv) ----------
__device__ __forceinline__ void asti(int* p, int v) {
  __hip_atomic_store(p, v, __ATOMIC_RELAXED, __HIP_MEMORY_SCOPE_AGENT);
}
__device__ __forceinline__ int aldi(int* p) {
  return __hip_atomic_load(p, __ATOMIC_RELAXED, __HIP_MEMORY_SCOPE_AGENT);
}
union MS { unsigned long long u; float2 f; };
__device__ __forceinline__ void astms(unsigned long long* p, float m, float s) {
  MS x; x.f.x = m; x.f.y = s;
  __hip_atomic_store(p, x.u, __ATOMIC_RELAXED, __HIP_MEMORY_SCOPE_AGENT);
}
__device__ __forceinline__ float2 aldms(unsigned long long* p) {
  MS x; x.u = __hip_atomic_load(p, __ATOMIC_RELAXED, __HIP_MEMORY_SCOPE_AGENT);
  return x.f;
}
// tagged 8B (value, generation) — only for the tiny L3-resident colL array
union TV { unsigned long long u; struct { float v; unsigned g; } p; };
__device__ __forceinline__ TV tvload(const unsigned long long* p) {
  TV x; x.u = __hip_atomic_load((unsigned long long*)p, __ATOMIC_RELAXED, __HIP_MEMORY_SCOPE_AGENT);
  return x;
}
__device__ __forceinline__ void tvstore(unsigned long long* p, float v, unsigned g) {
  TV x; x.p.v = v; x.p.g = g;
  __hip_atomic_store(p, x.u, __ATOMIC_RELAXED, __HIP_MEMORY_SCOPE_AGENT);
}

// ---------- numpy pairwise sum-of-squares over 768 contiguous f32 ----------
__device__ __forceinline__ float np_base96_sq(const float* a) {
  float r[8];
#pragma unroll
  for (int j = 0; j < 8; ++j) r[j] = __fmul_rn(a[j], a[j]);
  for (int i = 8; i < 96; i += 8) {
#pragma unroll
    for (int j = 0; j < 8; ++j) r[j] = __fadd_rn(r[j], __fmul_rn(a[i + j], a[i + j]));
  }
  float c01 = __fadd_rn(r[0], r[1]);
  float c23 = __fadd_rn(r[2], r[3]);
  float c45 = __fadd_rn(r[4], r[5]);
  float c67 = __fadd_rn(r[6], r[7]);
  return __fadd_rn(__fadd_rn(c01, c23), __fadd_rn(c45, c67));
}
__device__ __forceinline__ float np_ssq768(const float* a) {
  float L[8];
#pragma unroll
  for (int t = 0; t < 8; ++t) L[t] = np_base96_sq(a + 96 * t);
  float a01 = __fadd_rn(L[0], L[1]);
  float a23 = __fadd_rn(L[2], L[3]);
  float a45 = __fadd_rn(L[4], L[5]);
  float a67 = __fadd_rn(L[6], L[7]);
  return __fadd_rn(__fadd_rn(a01, a23), __fadd_rn(a45, a67));
}

__global__ __launch_bounds__(64) void rows_ssq(const float* __restrict__ a,
                                               float* __restrict__ out, int nrows) {
  int row = blockIdx.x * 64 + threadIdx.x;
  if (row < nrows) out[row] = np_ssq768(a + (size_t)row * EDIM);
}

// ---------- GEMM: dot = sequential ascending-k f32 FMA chain; assemble d / lq0 ----------
#define BM 128
#define BN 128
#define BK 16
template <bool LAYER0>
__global__ __launch_bounds__(256) void gemm_d(const float* __restrict__ A,
                                              const float* __restrict__ B,
                                              const float* __restrict__ sumrr,
                                              const float* __restrict__ sumee,
                                              float* __restrict__ V) {
  __shared__ float As[BK][BM];
  __shared__ float Bs[BK][BN];
  int tid = threadIdx.x;
  int bm = blockIdx.y * BM;
  int bn = blockIdx.x * BN;
  int lr = tid >> 1;
  int lc = (tid & 1) << 3;
  const float* Ap = A + (size_t)(bm + lr) * EDIM + lc;
  const float* Bp = B + (size_t)(bn + lr) * EDIM + lc;
  float acc[8][8];
#pragma unroll
  for (int i = 0; i < 8; ++i)
#pragma unroll
    for (int j = 0; j < 8; ++j) acc[i][j] = 0.f;
  int ty = tid >> 4, tx = tid & 15;
  for (int k0 = 0; k0 < EDIM; k0 += BK) {
    float4 a0 = *(const float4*)(Ap + k0);
    float4 a1 = *(const float4*)(Ap + k0 + 4);
    float4 b0 = *(const float4*)(Bp + k0);
    float4 b1 = *(const float4*)(Bp + k0 + 4);
    __syncthreads();
    As[lc + 0][lr] = a0.x; As[lc + 1][lr] = a0.y; As[lc + 2][lr] = a0.z; As[lc + 3][lr] = a0.w;
    As[lc + 4][lr] = a1.x; As[lc + 5][lr] = a1.y; As[lc + 6][lr] = a1.z; As[lc + 7][lr] = a1.w;
    Bs[lc + 0][lr] = b0.x; Bs[lc + 1][lr] = b0.y; Bs[lc + 2][lr] = b0.z; Bs[lc + 3][lr] = b0.w;
    Bs[lc + 4][lr] = b1.x; Bs[lc + 5][lr] = b1.y; Bs[lc + 6][lr] = b1.z; Bs[lc + 7][lr] = b1.w;
    __syncthreads();
#pragma unroll
    for (int k = 0; k < BK; ++k) {
      float av[8], bv[8];
      *(float4*)(av)     = *(const float4*)(&As[k][ty * 8]);
      *(float4*)(av + 4) = *(const float4*)(&As[k][ty * 8 + 4]);
      *(float4*)(bv)     = *(const float4*)(&Bs[k][tx * 8]);
      *(float4*)(bv + 4) = *(const float4*)(&Bs[k][tx * 8 + 4]);
#pragma unroll
      for (int i = 0; i < 8; ++i)
#pragma unroll
        for (int j = 0; j < 8; ++j) acc[i][j] = __fmaf_rn(av[i], bv[j], acc[i][j]);
    }
  }
#pragma unroll
  for (int i = 0; i < 8; ++i) {
    int row = bm + ty * 8 + i;
    float srr = sumrr[row];
    float* Vp = V + (size_t)row * NCODES + bn + tx * 8;
#pragma unroll
    for (int j = 0; j < 8; ++j) {
      int col = bn + tx * 8 + j;
      float s1 = __fadd_rn(srr, sumee[col]);
      float dv = __fsub_rn(s1, __fmul_rn(2.0f, acc[i][j]));
      Vp[j] = LAYER0 ? dv : __fdiv_rn(-dv, 0.003f);
    }
  }
}

// ---------- online f32 LSE helpers: SINGLE-exp branchless (bit-exact, round-14 proven) ----------
__device__ __forceinline__ void accf(float w, float& m, float& s) {
  float d = __fsub_rn(w, m);
  float e = expf(-fabsf(d));
  bool gt = (w > m);
  s = gt ? __fadd_rn(__fmul_rn(s, e), 1.0f) : __fadd_rn(s, e);
  m = gt ? w : m;
}
__device__ __forceinline__ void mergef(float mo, float so, float& m, float& s) {
  float mn = fmaxf(m, mo);
  if (mn == -INFINITY) { s = 0.f; return; }
  float d = __fsub_rn(mo, m);
  float e = expf(-fabsf(d));
  bool gt = (mo > m);
  s = gt ? __fadd_rn(__fmul_rn(s, e), so) : __fadd_rn(s, __fmul_rn(so, e));
  m = mn;
}

// ---------- persistent Sinkhorn: per-grp pipelined merge across 8 waves ----------
// Arrival: partial stores -> drain -> parr[b]; wave8 of blocks 0-7 folds 32 parr ->
// xarr[x]. Merge: wave g (g<8) polls ONLY xarr[g] and merges grp g's 4 column
// chains (lanes 0-3, round-4 exact q-ascending order) as soon as ITS 32 chunks
// arrived — overlapping later stragglers. Chains post to LDS + tagged LDS flag;
// wave0 folds grp 0..7 ascending (identical ops/order) and publishes tagged cT.
// Release: every thread polls its own cT[tid] (value rides with tag).
__global__ __launch_bounds__(1024) void sk_persist(float* __restrict__ lq,
                                                   unsigned long long* __restrict__ part,
                                                   unsigned long long* __restrict__ cT,
                                                   int* __restrict__ parr,
                                                   int* __restrict__ xarr,
                                                   unsigned gen0) {
  extern __shared__ float lds[];
  float (*vL)[NCODES] = (float(*)[NCODES])lds;     // 32 x 1024 staging (128 KB)
  float* rowLs = lds + 32 * NCODES;                // 32
  float* mM = rowLs + 32;                          // 8 x 4 (grp-major)
  float* sS = mM + 32;                             // 8 x 4
  volatile int* ldsdone = (volatile int*)(sS + 32);// 8 tagged LDS flags
  int tid = threadIdx.x, b = blockIdx.x;
  int wave = tid >> 6, lane = tid & 63;
  int r0 = b * ROWS_PB;

  if (tid < 8) ldsdone[tid] = 0;   // init before first arrival barrier

  float v[32];
#pragma unroll
  for (int r = 0; r < 32; ++r) v[r] = lq[(size_t)(r0 + r) * NCODES + tid];

#define COLCHAIN_ARRIVE(GEN)                                                  \
  do {                                                                        \
    float m = -INFINITY, s = 0.f;                                             \
    _Pragma("unroll")                                                         \
    for (int r = 0; r < 32; ++r) accf(v[r], m, s);                            \
    astms(&part[(size_t)b * NCODES + tid], m, s);                             \
    asm volatile("s_waitcnt vmcnt(0)" ::: "memory");                          \
    __syncthreads();                                                          \
    if (tid == 0) asti(&parr[b * 16], (GEN));                                 \
  } while (0)

  COLCHAIN_ARRIVE(1);

  for (int t = 0; t < SKITERS; ++t) {
    int gen = t + 1;                       // parr/xarr generation (per-layer regions)
    unsigned cg = gen0 + (unsigned)gen;    // cT generation (monotonic across layers)

    // ---- aggregator: wave 8 of blocks 0-7 folds its 32 parr flags -> xarr[b] ----
    if (b < 8 && wave == 8) {
      if (lane < 32) {
        int* fl = &parr[(b * 32 + lane) * 16];
        while (aldi(fl) < gen) __builtin_amdgcn_s_sleep(1);
      }
      asm volatile("" ::: "memory");
      if (lane == 0) asti(&xarr[b * 16], gen);
    }

    // ---- per-grp merge: wave g handles grp g (4 col chains on lanes 0-3) ----
    if (wave < 8) {
      // all lanes poll the single xarr[wave] line (coalesced same-address load)
      {
        int* fl = &xarr[wave * 16];
        while (aldi(fl) < gen) __builtin_amdgcn_s_sleep(1);
      }
      asm volatile("" ::: "memory");
      if (lane < 4) {
        int col = 4 * b + lane;
        float m = -INFINITY, s = 0.f;
#pragma unroll
        for (int qb = 0; qb < 32; qb += 16) {
          float2 pv[16];
#pragma unroll
          for (int q = 0; q < 16; ++q)
            pv[q] = aldms(&part[(size_t)(wave * 32 + qb + q) * NCODES + col]);
#pragma unroll
          for (int q = 0; q < 16; ++q) mergef(pv[q].x, pv[q].y, m, s);
        }
        mM[wave * 4 + lane] = m;
        sS[wave * 4 + lane] = s;
      }
      asm volatile("s_waitcnt lgkmcnt(0)" ::: "memory");
      if (lane == 0) ldsdone[wave] = gen;
    }

    // ---- wave0: fold grp 0..7 ascending (identical order) and publish cT ----
    if (wave == 0) {
      for (;;) {
        int ok = 1;
        if (lane < 8) ok = (ldsdone[lane] >= gen);
        if (__all(ok)) break;
        __builtin_amdgcn_s_sleep(1);
      }
      asm volatile("" ::: "memory");
      if (lane < 4) {
        float mm = -INFINITY, ss = 0.f;
#pragma unroll
        for (int g2 = 0; g2 < 8; ++g2)
          mergef(mM[g2 * 4 + lane], sS[g2 * 4 + lane], mm, ss);
        tvstore(&cT[4 * b + lane], __fadd_rn(logf(ss), mm), cg);
      }
    }

    // ---- every thread polls ITS column's tagged colL (value rides with tag) ----
    float cl;
    {
      TV cv = tvload(&cT[tid]);
      while (cv.p.g < cg) { __builtin_amdgcn_s_sleep(1); cv = tvload(&cT[tid]); }
      cl = cv.p.v;
    }

    // ---- column subtract + stage (identical ops to round 14/16) ----
#pragma unroll
    for (int r = 0; r < 32; ++r) {
      v[r] = __fsub_rn(v[r], cl);
      vL[r][tid] = v[r];
    }
    __syncthreads();

    // ---- row phase: wave w reduces rows 2w, 2w+1 (round-4 exact tree) ----
#pragma unroll
    for (int rr = 0; rr < 2; ++rr) {
      int row = wave * 2 + rr;
      float vals[16];
#pragma unroll
      for (int k = 0; k < 16; ++k) vals[k] = vL[row][lane + (k << 6)];
      float mx = vals[0];
#pragma unroll
      for (int k = 1; k < 16; ++k) mx = fmaxf(mx, vals[k]);
      for (int off = 32; off; off >>= 1) mx = fmaxf(mx, __shfl_xor(mx, off, 64));
      float s = 0.f;
#pragma unroll
      for (int k = 0; k < 16; ++k) s = __fadd_rn(s, expf(__fsub_rn(vals[k], mx)));
      for (int off = 32; off; off >>= 1) s = __fadd_rn(s, __shfl_xor(s, off, 64));
      if (lane == 0) rowLs[row] = __fadd_rn(logf(s), mx);
    }
    __syncthreads();
#pragma unroll
    for (int r = 0; r < 32; ++r) v[r] = __fsub_rn(v[r], rowLs[r]);

    if (t < SKITERS - 1) COLCHAIN_ARRIVE(gen + 1);
  }

  // write final lq back for the epilogue (coalesced: tid spans columns)
#pragma unroll
  for (int r = 0; r < 32; ++r) lq[(size_t)(r0 + r) * NCODES + tid] = v[r];
#undef COLCHAIN_ARRIVE
}

// ---------- epilogue: argmin(d) / argmax(lq), gather, f32 residual, ssq ----------
template <int MODE>   // 0: argmin, 1: argmax
__global__ __launch_bounds__(256) void epi(const float* __restrict__ V,
                                           const float* __restrict__ rin,
                                           const float* __restrict__ cb,
                                           float* __restrict__ rout,
                                           double* __restrict__ rowssq,
                                           float* __restrict__ idx_out,
                                           int layer) {
  int i = blockIdx.x;
  int tid = threadIdx.x;
  const float* Vrow = V + (size_t)i * NCODES;
  float bv = MODE ? -INFINITY : INFINITY;
  int bj = 0;
  for (int j = tid; j < NCODES; j += 256) {
    float v = Vrow[j];
    bool better = MODE ? (v > bv) : (v < bv);
    if (better) { bv = v; bj = j; }
  }
  __shared__ float sv[256];
  __shared__ int   sj[256];
  sv[tid] = bv; sj[tid] = bj;
  __syncthreads();
  for (int st = 128; st; st >>= 1) {
    if (tid < st) {
      float v2 = sv[tid + st]; int j2 = sj[tid + st];
      bool better = MODE ? (v2 > sv[tid]) : (v2 < sv[tid]);
      if (better || (v2 == sv[tid] && j2 < sj[tid])) { sv[tid] = v2; sj[tid] = j2; }
    }
    __syncthreads();
  }
  int idx = sj[0];
  const float* crow = cb + (size_t)idx * EDIM;
  double p = 0.0;
  for (int c = tid; c < EDIM; c += 256) {
    float rn = __fsub_rn(rin[(size_t)i * EDIM + c], crow[c]);
    rout[(size_t)i * EDIM + c] = rn;
    p += (double)rn * (double)rn;
  }
  for (int off = 32; off; off >>= 1) p += __shfl_xor(p, off, 64);
  __shared__ double wsum[4];
  if ((tid & 63) == 0) wsum[tid >> 6] = p;
  __syncthreads();
  if (tid == 0) {
    rowssq[i] = wsum[0] + wsum[1] + wsum[2] + wsum[3];
    idx_out[(size_t)i * 4 + layer] = (float)idx;
  }
}

// ---------- final loss ----------
__global__ __launch_bounds__(1024) void loss_final(const double* __restrict__ rowssq,
                                                   float* __restrict__ out_loss) {
  int tid = threadIdx.x;
  __shared__ double acc[16];
  __shared__ double ltot;
  if (tid == 0) ltot = 0.0;
  __syncthreads();
  for (int l = 0; l < 4; ++l) {
    double p = 0.0;
    for (int i = tid; i < N_VEC; i += 1024) p += rowssq[l * N_VEC + i];
    for (int off = 32; off; off >>= 1) p += __shfl_xor(p, off, 64);
    if ((tid & 63) == 0) acc[tid >> 6] = p;
    __syncthreads();
    if (tid == 0) {
      double sl = 0.0;
      for (int w = 0; w < 16; ++w) sl += acc[w];
      ltot += 2.0 * sl / ((double)N_VEC * (double)EDIM);
    }
    __syncthreads();
  }
  if (tid == 0) out_loss[0] = (float)(ltot * 0.25);
}

// ---------- x_q = x - resid ----------
__global__ __launch_bounds__(256) void xq_final(const float* __restrict__ x,
                                                float* __restrict__ out) {
  size_t i = ((size_t)blockIdx.x * 256 + threadIdx.x) * 4;
  float4 xv = *(const float4*)(x + i);
  float4 rv = *(const float4*)(out + i);
  float4 o;
  o.x = __fsub_rn(xv.x, rv.x); o.y = __fsub_rn(xv.y, rv.y);
  o.z = __fsub_rn(xv.z, rv.z); o.w = __fsub_rn(xv.w, rv.w);
  *(float4*)(out + i) = o;
}

extern "C" void kernel_launch(void* const* d_in, const int* in_sizes, int n_in,
                              void* d_out, int out_size, void* d_ws, size_t ws_size,
                              hipStream_t stream) {
  const float* x = (const float*)d_in[0];
  const float* cbs[4] = {(const float*)d_in[1], (const float*)d_in[2],
                         (const float*)d_in[3], (const float*)d_in[4]};
  float* out = (float*)d_out;
  float* resid = out;                                   // reuse x_q region as residual
  float* loss_out = out + (size_t)N_VEC * EDIM;
  float* idx_out = loss_out + 1;

  float* ws = (float*)d_ws;
  float* lq = ws;                                       // N*K f32      (32 MB)
  unsigned long long* part = (unsigned long long*)(lq + (size_t)N_VEC * NCODES); // 2 MB
  unsigned long long* cT = part + (size_t)CHUNKS * NCODES;                       // 8 KB
  float* sumrr = (float*)(cT + NCODES);                 // N
  float* sumee = sumrr + N_VEC;                         // 4*K
  double* rowssq = (double*)(sumee + 4 * NCODES);       // 4*N doubles (8-aligned)
  int* flagbase = (int*)(rowssq + 4 * N_VEC);           // 4 layers x 8192 ints

  static int lds_set = 0;
  if (!lds_set) {   // idempotent host-side attribute config (safe under capture)
    hipFuncSetAttribute((const void*)sk_persist,
                        hipFuncAttributeMaxDynamicSharedMemorySize, DYN_LDS);
    lds_set = 1;
  }

  // zero cT tags (poison would read as "ready") + all per-layer flag regions
  hipMemsetAsync(cT, 0, NCODES * 8, stream);
  hipMemsetAsync(flagbase, 0, 4 * 8192 * sizeof(int), stream);

  for (int l = 0; l < 4; ++l)
    rows_ssq<<<NCODES / 64, 64, 0, stream>>>(cbs[l], sumee + l * NCODES, NCODES);
  rows_ssq<<<N_VEC / 64, 64, 0, stream>>>(x, sumrr, N_VEC);

  for (int l = 0; l < 4; ++l) {
    const float* rin = (l == 0) ? x : resid;
    if (l == 0) {
      gemm_d<true><<<dim3(NCODES / BN, N_VEC / BM), 256, 0, stream>>>(rin, cbs[l], sumrr, sumee + l * NCODES, lq);
      epi<0><<<N_VEC, 256, 0, stream>>>(lq, rin, cbs[l], resid, rowssq + (size_t)l * N_VEC, idx_out, l);
    } else {
      gemm_d<false><<<dim3(NCODES / BN, N_VEC / BM), 256, 0, stream>>>(rin, cbs[l], sumrr, sumee + l * NCODES, lq);
      int* lf = flagbase + l * 8192;
      sk_persist<<<CHUNKS, 1024, DYN_LDS, stream>>>(lq, part, cT,
                                                    lf, lf + 4096, (unsigned)(256 * l));
      epi<1><<<N_VEC, 256, 0, stream>>>(lq, rin, cbs[l], resid, rowssq + (size_t)l * N_VEC, idx_out, l);
    }
    if (l < 3)
      rows_ssq<<<N_VEC / 64, 64, 0, stream>>>(resid, sumrr, N_VEC);
  }
  loss_final<<<1, 1024, 0, stream>>>(rowssq, loss_out);
  xq_final<<<(N_VEC * EDIM / 4) / 256, 256, 0, stream>>>(x, out);
}

// Round 18
// 6420.370 us; speedup vs baseline: 1.1485x; 1.1485x over previous
//
#include <hip/hip_runtime.h>
#include <math.h>

#define N_VEC   8192
#define EDIM    768
#define NCODES  1024
#define SKITERS 100
#define ROWS_PB 32
#define CHUNKS  (N_VEC / ROWS_PB)   // 256
#define DYN_LDS ((32 * NCODES + 32) * 4)

// ---------- agent-scope relaxed atomics (coherent at L3, no L2 wb/inv) ----------
__device__ __forceinline__ void asti(int* p, int v) {
  __hip_atomic_store(p, v, __ATOMIC_RELAXED, __HIP_MEMORY_SCOPE_AGENT);
}
__device__ __forceinline__ int aldi(int* p) {
  return __hip_atomic_load(p, __ATOMIC_RELAXED, __HIP_MEMORY_SCOPE_AGENT);
}
union MS { unsigned long long u; float2 f; };
__device__ __forceinline__ void astms(unsigned long long* p, float m, float s) {
  MS x; x.f.x = m; x.f.y = s;
  __hip_atomic_store(p, x.u, __ATOMIC_RELAXED, __HIP_MEMORY_SCOPE_AGENT);
}
__device__ __forceinline__ float2 aldms(unsigned long long* p) {
  MS x; x.u = __hip_atomic_load(p, __ATOMIC_RELAXED, __HIP_MEMORY_SCOPE_AGENT);
  return x.f;
}
// tagged 8B (value, generation) — only for the tiny L3-resident colL array
union TV { unsigned long long u; struct { float v; unsigned g; } p; };
__device__ __forceinline__ TV tvload(const unsigned long long* p) {
  TV x; x.u = __hip_atomic_load((unsigned long long*)p, __ATOMIC_RELAXED, __HIP_MEMORY_SCOPE_AGENT);
  return x;
}
__device__ __forceinline__ void tvstore(unsigned long long* p, float v, unsigned g) {
  TV x; x.p.v = v; x.p.g = g;
  __hip_atomic_store(p, x.u, __ATOMIC_RELAXED, __HIP_MEMORY_SCOPE_AGENT);
}

// ---------- numpy pairwise sum-of-squares over 768 contiguous f32 ----------
__device__ __forceinline__ float np_base96_sq(const float* a) {
  float r[8];
#pragma unroll
  for (int j = 0; j < 8; ++j) r[j] = __fmul_rn(a[j], a[j]);
  for (int i = 8; i < 96; i += 8) {
#pragma unroll
    for (int j = 0; j < 8; ++j) r[j] = __fadd_rn(r[j], __fmul_rn(a[i + j], a[i + j]));
  }
  float c01 = __fadd_rn(r[0], r[1]);
  float c23 = __fadd_rn(r[2], r[3]);
  float c45 = __fadd_rn(r[4], r[5]);
  float c67 = __fadd_rn(r[6], r[7]);
  return __fadd_rn(__fadd_rn(c01, c23), __fadd_rn(c45, c67));
}
__device__ __forceinline__ float np_ssq768(const float* a) {
  float L[8];
#pragma unroll
  for (int t = 0; t < 8; ++t) L[t] = np_base96_sq(a + 96 * t);
  float a01 = __fadd_rn(L[0], L[1]);
  float a23 = __fadd_rn(L[2], L[3]);
  float a45 = __fadd_rn(L[4], L[5]);
  float a67 = __fadd_rn(L[6], L[7]);
  return __fadd_rn(__fadd_rn(a01, a23), __fadd_rn(a45, a67));
}

__global__ __launch_bounds__(64) void rows_ssq(const float* __restrict__ a,
                                               float* __restrict__ out, int nrows) {
  int row = blockIdx.x * 64 + threadIdx.x;
  if (row < nrows) out[row] = np_ssq768(a + (size_t)row * EDIM);
}

// ---------- GEMM: dot = sequential ascending-k f32 FMA chain; assemble d / lq0 ----------
#define BM 128
#define BN 128
#define BK 16
template <bool LAYER0>
__global__ __launch_bounds__(256) void gemm_d(const float* __restrict__ A,
                                              const float* __restrict__ B,
                                              const float* __restrict__ sumrr,
                                              const float* __restrict__ sumee,
                                              float* __restrict__ V) {
  __shared__ float As[BK][BM];
  __shared__ float Bs[BK][BN];
  int tid = threadIdx.x;
  int bm = blockIdx.y * BM;
  int bn = blockIdx.x * BN;
  int lr = tid >> 1;
  int lc = (tid & 1) << 3;
  const float* Ap = A + (size_t)(bm + lr) * EDIM + lc;
  const float* Bp = B + (size_t)(bn + lr) * EDIM + lc;
  float acc[8][8];
#pragma unroll
  for (int i = 0; i < 8; ++i)
#pragma unroll
    for (int j = 0; j < 8; ++j) acc[i][j] = 0.f;
  int ty = tid >> 4, tx = tid & 15;
  for (int k0 = 0; k0 < EDIM; k0 += BK) {
    float4 a0 = *(const float4*)(Ap + k0);
    float4 a1 = *(const float4*)(Ap + k0 + 4);
    float4 b0 = *(const float4*)(Bp + k0);
    float4 b1 = *(const float4*)(Bp + k0 + 4);
    __syncthreads();
    As[lc + 0][lr] = a0.x; As[lc + 1][lr] = a0.y; As[lc + 2][lr] = a0.z; As[lc + 3][lr] = a0.w;
    As[lc + 4][lr] = a1.x; As[lc + 5][lr] = a1.y; As[lc + 6][lr] = a1.z; As[lc + 7][lr] = a1.w;
    Bs[lc + 0][lr] = b0.x; Bs[lc + 1][lr] = b0.y; Bs[lc + 2][lr] = b0.z; Bs[lc + 3][lr] = b0.w;
    Bs[lc + 4][lr] = b1.x; Bs[lc + 5][lr] = b1.y; Bs[lc + 6][lr] = b1.z; Bs[lc + 7][lr] = b1.w;
    __syncthreads();
#pragma unroll
    for (int k = 0; k < BK; ++k) {
      float av[8], bv[8];
      *(float4*)(av)     = *(const float4*)(&As[k][ty * 8]);
      *(float4*)(av + 4) = *(const float4*)(&As[k][ty * 8 + 4]);
      *(float4*)(bv)     = *(const float4*)(&Bs[k][tx * 8]);
      *(float4*)(bv + 4) = *(const float4*)(&Bs[k][tx * 8 + 4]);
#pragma unroll
      for (int i = 0; i < 8; ++i)
#pragma unroll
        for (int j = 0; j < 8; ++j) acc[i][j] = __fmaf_rn(av[i], bv[j], acc[i][j]);
    }
  }
#pragma unroll
  for (int i = 0; i < 8; ++i) {
    int row = bm + ty * 8 + i;
    float srr = sumrr[row];
    float* Vp = V + (size_t)row * NCODES + bn + tx * 8;
#pragma unroll
    for (int j = 0; j < 8; ++j) {
      int col = bn + tx * 8 + j;
      float s1 = __fadd_rn(srr, sumee[col]);
      float dv = __fsub_rn(s1, __fmul_rn(2.0f, acc[i][j]));
      Vp[j] = LAYER0 ? dv : __fdiv_rn(-dv, 0.003f);
    }
  }
}

// ---------- online f32 LSE helpers: SINGLE-exp branchless (bit-exact, round-14 proven) ----------
__device__ __forceinline__ void accf(float w, float& m, float& s) {
  float d = __fsub_rn(w, m);
  float e = expf(-fabsf(d));
  bool gt = (w > m);
  s = gt ? __fadd_rn(__fmul_rn(s, e), 1.0f) : __fadd_rn(s, e);
  m = gt ? w : m;
}
__device__ __forceinline__ void mergef(float mo, float so, float& m, float& s) {
  float mn = fmaxf(m, mo);
  if (mn == -INFINITY) { s = 0.f; return; }
  float d = __fsub_rn(mo, m);
  float e = expf(-fabsf(d));
  bool gt = (mo > m);
  s = gt ? __fadd_rn(__fmul_rn(s, e), so) : __fadd_rn(s, __fmul_rn(so, e));
  m = mn;
}

// ---------- persistent Sinkhorn: r16 structure; aggregation moved off critical path ----------
// Arrival: partial stores -> drain -> parr[b]; WAVE 8 of blocks 0-7 folds 32 parr ->
// xarr[x] (was wave0 — those 8 blocks produce cT cols 0-31 which gate everyone,
// so their serial agg step sat on the global critical path). Merge: wave0 polls
// 8 xarr, merges this block's 4 columns (round-4 exact chain order), publishes
// tagged cT. Release: every thread polls its own cT[tid] (value rides with tag).
__global__ __launch_bounds__(1024) void sk_persist(float* __restrict__ lq,
                                                   unsigned long long* __restrict__ part,
                                                   unsigned long long* __restrict__ cT,
                                                   int* __restrict__ parr,
                                                   int* __restrict__ xarr,
                                                   unsigned gen0) {
  extern __shared__ float lds[];
  float (*vL)[NCODES] = (float(*)[NCODES])lds;     // 32 x 1024 staging (128 KB)
  float* rowLs = lds + 32 * NCODES;                // 32
  int tid = threadIdx.x, b = blockIdx.x;
  int wave = tid >> 6, lane = tid & 63;
  int r0 = b * ROWS_PB;

  float v[32];
#pragma unroll
  for (int r = 0; r < 32; ++r) v[r] = lq[(size_t)(r0 + r) * NCODES + tid];

#define COLCHAIN_ARRIVE(GEN)                                                  \
  do {                                                                        \
    float m = -INFINITY, s = 0.f;                                             \
    _Pragma("unroll")                                                         \
    for (int r = 0; r < 32; ++r) accf(v[r], m, s);                            \
    astms(&part[(size_t)b * NCODES + tid], m, s);                             \
    asm volatile("s_waitcnt vmcnt(0)" ::: "memory");                          \
    __syncthreads();                                                          \
    if (tid == 0) asti(&parr[b * 16], (GEN));                                 \
  } while (0)

  COLCHAIN_ARRIVE(1);

  for (int t = 0; t < SKITERS; ++t) {
    int gen = t + 1;                       // parr/xarr generation (per-layer regions)
    unsigned cg = gen0 + (unsigned)gen;    // cT generation (monotonic across layers)

    // ---- aggregators: WAVE 8 of blocks 0-7 folds 32 parr flags into xarr[b] ----
    if (b < 8 && wave == 8) {
      if (lane < 32) {
        int* fl = &parr[(b * 32 + lane) * 16];
        while (aldi(fl) < gen) __builtin_amdgcn_s_sleep(1);
      }
      asm volatile("" ::: "memory");
      if (lane == 0) asti(&xarr[b * 16], gen);
    }

    if (wave == 0) {
      // all blocks: wait for the 8 XCD-level arrival flags
      if (lane < 8) {
        int* fl = &xarr[lane * 16];
        while (aldi(fl) < gen) __builtin_amdgcn_s_sleep(1);
      }
      asm volatile("" ::: "memory");
      // merge this block's 4 columns (round-4 exact chain order)
      float m = -INFINITY, s = 0.f;
      if (lane < 32) {
        int colj = lane >> 3, grp = lane & 7;
        int col = 4 * b + colj;
#pragma unroll
        for (int qb = 0; qb < 32; qb += 16) {
          float2 pv[16];
#pragma unroll
          for (int q = 0; q < 16; ++q)
            pv[q] = aldms(&part[(size_t)(grp * 32 + qb + q) * NCODES + col]);
#pragma unroll
          for (int q = 0; q < 16; ++q) mergef(pv[q].x, pv[q].y, m, s);
        }
      }
      // 8-way final merge in grp order via wave shuffles (lanes 0-3 use result)
      float mm = -INFINITY, ss = 0.f;
#pragma unroll
      for (int g2 = 0; g2 < 8; ++g2) {
        float mo = __shfl(m, ((lane & 3) << 3) + g2, 64);
        float so = __shfl(s, ((lane & 3) << 3) + g2, 64);
        mergef(mo, so, mm, ss);
      }
      if (lane < 4) tvstore(&cT[4 * b + lane], __fadd_rn(logf(ss), mm), cg);
    }

    // ---- every thread polls ITS column's tagged colL (value rides with tag) ----
    float cl;
    {
      TV cv = tvload(&cT[tid]);
      while (cv.p.g < cg) { __builtin_amdgcn_s_sleep(1); cv = tvload(&cT[tid]); }
      cl = cv.p.v;
    }

    // ---- column subtract + stage (identical ops to round 14/16) ----
#pragma unroll
    for (int r = 0; r < 32; ++r) {
      v[r] = __fsub_rn(v[r], cl);
      vL[r][tid] = v[r];
    }
    __syncthreads();

    // ---- row phase: wave w reduces rows 2w, 2w+1 (round-4 exact tree) ----
#pragma unroll
    for (int rr = 0; rr < 2; ++rr) {
      int row = wave * 2 + rr;
      float vals[16];
#pragma unroll
      for (int k = 0; k < 16; ++k) vals[k] = vL[row][lane + (k << 6)];
      float mx = vals[0];
#pragma unroll
      for (int k = 1; k < 16; ++k) mx = fmaxf(mx, vals[k]);
      for (int off = 32; off; off >>= 1) mx = fmaxf(mx, __shfl_xor(mx, off, 64));
      float s = 0.f;
#pragma unroll
      for (int k = 0; k < 16; ++k) s = __fadd_rn(s, expf(__fsub_rn(vals[k], mx)));
      for (int off = 32; off; off >>= 1) s = __fadd_rn(s, __shfl_xor(s, off, 64));
      if (lane == 0) rowLs[row] = __fadd_rn(logf(s), mx);
    }
    __syncthreads();
#pragma unroll
    for (int r = 0; r < 32; ++r) v[r] = __fsub_rn(v[r], rowLs[r]);

    if (t < SKITERS - 1) COLCHAIN_ARRIVE(gen + 1);
  }

  // write final lq back for the epilogue (coalesced: tid spans columns)
#pragma unroll
  for (int r = 0; r < 32; ++r) lq[(size_t)(r0 + r) * NCODES + tid] = v[r];
#undef COLCHAIN_ARRIVE
}

// ---------- epilogue: argmin(d) / argmax(lq), gather, f32 residual, ssq ----------
template <int MODE>   // 0: argmin, 1: argmax
__global__ __launch_bounds__(256) void epi(const float* __restrict__ V,
                                           const float* __restrict__ rin,
                                           const float* __restrict__ cb,
                                           float* __restrict__ rout,
                                           double* __restrict__ rowssq,
                                           float* __restrict__ idx_out,
                                           int layer) {
  int i = blockIdx.x;
  int tid = threadIdx.x;
  const float* Vrow = V + (size_t)i * NCODES;
  float bv = MODE ? -INFINITY : INFINITY;
  int bj = 0;
  for (int j = tid; j < NCODES; j += 256) {
    float v = Vrow[j];
    bool better = MODE ? (v > bv) : (v < bv);
    if (better) { bv = v; bj = j; }
  }
  __shared__ float sv[256];
  __shared__ int   sj[256];
  sv[tid] = bv; sj[tid] = bj;
  __syncthreads();
  for (int st = 128; st; st >>= 1) {
    if (tid < st) {
      float v2 = sv[tid + st]; int j2 = sj[tid + st];
      bool better = MODE ? (v2 > sv[tid]) : (v2 < sv[tid]);
      if (better || (v2 == sv[tid] && j2 < sj[tid])) { sv[tid] = v2; sj[tid] = j2; }
    }
    __syncthreads();
  }
  int idx = sj[0];
  const float* crow = cb + (size_t)idx * EDIM;
  double p = 0.0;
  for (int c = tid; c < EDIM; c += 256) {
    float rn = __fsub_rn(rin[(size_t)i * EDIM + c], crow[c]);
    rout[(size_t)i * EDIM + c] = rn;
    p += (double)rn * (double)rn;
  }
  for (int off = 32; off; off >>= 1) p += __shfl_xor(p, off, 64);
  __shared__ double wsum[4];
  if ((tid & 63) == 0) wsum[tid >> 6] = p;
  __syncthreads();
  if (tid == 0) {
    rowssq[i] = wsum[0] + wsum[1] + wsum[2] + wsum[3];
    idx_out[(size_t)i * 4 + layer] = (float)idx;
  }
}

// ---------- final loss ----------
__global__ __launch_bounds__(1024) void loss_final(const double* __restrict__ rowssq,
                                                   float* __restrict__ out_loss) {
  int tid = threadIdx.x;
  __shared__ double acc[16];
  __shared__ double ltot;
  if (tid == 0) ltot = 0.0;
  __syncthreads();
  for (int l = 0; l < 4; ++l) {
    double p = 0.0;
    for (int i = tid; i < N_VEC; i += 1024) p += rowssq[l * N_VEC + i];
    for (int off = 32; off; off >>= 1) p += __shfl_xor(p, off, 64);
    if ((tid & 63) == 0) acc[tid >> 6] = p;
    __syncthreads();
    if (tid == 0) {
      double sl = 0.0;
      for (int w = 0; w < 16; ++w) sl += acc[w];
      ltot += 2.0 * sl / ((double)N_VEC * (double)EDIM);
    }
    __syncthreads();
  }
  if (tid == 0) out_loss[0] = (float)(ltot * 0.25);
}

// ---------- x_q = x - resid ----------
__global__ __launch_bounds__(256) void xq_final(const float* __restrict__ x,
                                                float* __restrict__ out) {
  size_t i = ((size_t)blockIdx.x * 256 + threadIdx.x) * 4;
  float4 xv = *(const float4*)(x + i);
  float4 rv = *(const float4*)(out + i);
  float4 o;
  o.x = __fsub_rn(xv.x, rv.x); o.y = __fsub_rn(xv.y, rv.y);
  o.z = __fsub_rn(xv.z, rv.z); o.w = __fsub_rn(xv.w, rv.w);
  *(float4*)(out + i) = o;
}

extern "C" void kernel_launch(void* const* d_in, const int* in_sizes, int n_in,
                              void* d_out, int out_size, void* d_ws, size_t ws_size,
                              hipStream_t stream) {
  const float* x = (const float*)d_in[0];
  const float* cbs[4] = {(const float*)d_in[1], (const float*)d_in[2],
                         (const float*)d_in[3], (const float*)d_in[4]};
  float* out = (float*)d_out;
  float* resid = out;                                   // reuse x_q region as residual
  float* loss_out = out + (size_t)N_VEC * EDIM;
  float* idx_out = loss_out + 1;

  float* ws = (float*)d_ws;
  float* lq = ws;                                       // N*K f32      (32 MB)
  unsigned long long* part = (unsigned long long*)(lq + (size_t)N_VEC * NCODES); // 2 MB
  unsigned long long* cT = part + (size_t)CHUNKS * NCODES;                       // 8 KB
  float* sumrr = (float*)(cT + NCODES);                 // N
  float* sumee = sumrr + N_VEC;                         // 4*K
  double* rowssq = (double*)(sumee + 4 * NCODES);       // 4*N doubles (8-aligned)
  int* flagbase = (int*)(rowssq + 4 * N_VEC);           // 4 layers x 8192 ints

  static int lds_set = 0;
  if (!lds_set) {   // idempotent host-side attribute config (safe under capture)
    hipFuncSetAttribute((const void*)sk_persist,
                        hipFuncAttributeMaxDynamicSharedMemorySize, DYN_LDS);
    lds_set = 1;
  }

  // zero cT tags (poison would read as "ready") + all per-layer flag regions
  hipMemsetAsync(cT, 0, NCODES * 8, stream);
  hipMemsetAsync(flagbase, 0, 4 * 8192 * sizeof(int), stream);

  for (int l = 0; l < 4; ++l)
    rows_ssq<<<NCODES / 64, 64, 0, stream>>>(cbs[l], sumee + l * NCODES, NCODES);
  rows_ssq<<<N_VEC / 64, 64, 0, stream>>>(x, sumrr, N_VEC);

  for (int l = 0; l < 4; ++l) {
    const float* rin = (l == 0) ? x : resid;
    if (l == 0) {
      gemm_d<true><<<dim3(NCODES / BN, N_VEC / BM), 256, 0, stream>>>(rin, cbs[l], sumrr, sumee + l * NCODES, lq);
      epi<0><<<N_VEC, 256, 0, stream>>>(lq, rin, cbs[l], resid, rowssq + (size_t)l * N_VEC, idx_out, l);
    } else {
      gemm_d<false><<<dim3(NCODES / BN, N_VEC / BM), 256, 0, stream>>>(rin, cbs[l], sumrr, sumee + l * NCODES, lq);
      int* lf = flagbase + l * 8192;
      sk_persist<<<CHUNKS, 1024, DYN_LDS, stream>>>(lq, part, cT,
                                                    lf, lf + 4096, (unsigned)(256 * l));
      epi<1><<<N_VEC, 256, 0, stream>>>(lq, rin, cbs[l], resid, rowssq + (size_t)l * N_VEC, idx_out, l);
    }
    if (l < 3)
      rows_ssq<<<N_VEC / 64, 64, 0, stream>>>(resid, sumrr, N_VEC);
  }
  loss_final<<<1, 1024, 0, stream>>>(rowssq, loss_out);
  xq_final<<<(N_VEC * EDIM / 4) / 256, 256, 0, stream>>>(x, out);
}